// Round 1
// baseline (1923.624 us; speedup 1.0000x reference)
//
#include <hip/hip_runtime.h>
#include <hip/hip_bf16.h>
#include <stdint.h>

typedef __hip_bfloat16 bf16_t;
typedef __attribute__((ext_vector_type(4))) float f32x4;
typedef __attribute__((ext_vector_type(8))) short s16x8;

#define UNITS 768
#define NCOLS 3072        // 4*UNITS (gates, reordered)
#define NPRED 96
#define MROWS 2048

__device__ __forceinline__ float sigf(float x) {
    return __builtin_amdgcn_rcpf(1.f + __expf(-x));
}
__device__ __forceinline__ float tanh_fast(float x) {
    return 1.f - 2.f * __builtin_amdgcn_rcpf(1.f + __expf(2.f * x));
}

// ---------------- prep kernels (once per launch, off critical path) ---------------

// B0T[c][k] = W_ih[g*768+u][k], c-reordered (linear), K=96
__global__ void prep_b0(const float* __restrict__ W_ih, bf16_t* __restrict__ B0T) {
    int idx = blockIdx.x * 256 + threadIdx.x;
    if (idx >= NCOLS * 96) return;
    int c = idx / 96, k = idx % 96;
    int u = ((c >> 6) << 4) + (c & 15);
    int g = (c >> 4) & 3;
    B0T[idx] = (bf16_t)W_ih[(g * UNITS + u) * 96 + k];
}

// x0 in A-fragment layout: elem((mf*3+kf)*512 + l*8 + j) = x[mf*16+(l&15)][kf*32+(l>>4)*8+j]
__global__ void prep_x0(const float* __restrict__ inputs, bf16_t* __restrict__ x0) {
    int idx = blockIdx.x * 256 + threadIdx.x; // 2048*96 = 196608 exactly
    int j = idx & 7;
    int l = (idx >> 3) & 63;
    int fg = idx >> 9;          // mf*3 + kf
    int kf = fg % 3;
    int mf = fg / 3;
    int m = mf * 16 + (l & 15);
    int k = kf * 32 + (l >> 4) * 8 + j;
    x0[idx] = (bf16_t)inputs[(m * 24 + 23) * 96 + k];
}

__global__ void prep_bias(const float* __restrict__ b_ih, const float* __restrict__ b_hh,
                          const float* __restrict__ W_ih, const float* __restrict__ b_d,
                          float* __restrict__ b0_r, float* __restrict__ beff_r) {
    int c = blockIdx.x * 256 + threadIdx.x;
    if (c >= NCOLS) return;
    int u = ((c >> 6) << 4) + (c & 15);
    int g = (c >> 4) & 3;
    int r = g * UNITS + u;
    float v = b_ih[r] + b_hh[r];
    float acc = 0.f;
    for (int j = 0; j < 96; ++j) acc += W_ih[r * 96 + j] * b_d[j];
    b0_r[c] = v;
    beff_r[c] = v + acc;
}

// BeffT[c][k] = W_hh[r(c)][k] + sum_j W_ih[r(c)][j]*W_d[j][k]   (c<3072, LDS-tiled)
__global__ void prep_beff2(const float* __restrict__ W_hh, const float* __restrict__ W_ih,
                           const float* __restrict__ W_d, bf16_t* __restrict__ BeffT) {
    __shared__ float sWih[64][96];
    __shared__ float sWd[96][64];
    const int c0 = blockIdx.x * 64, k0 = blockIdx.y * 64;
    const int tid = threadIdx.x;
    for (int i = tid; i < 64 * 96; i += 256) {
        int cc = i / 96, j = i % 96;
        int c = c0 + cc;
        int u = ((c >> 6) << 4) + (c & 15);
        int g = (c >> 4) & 3;
        sWih[cc][j] = W_ih[(g * UNITS + u) * 96 + j];
    }
    for (int i = tid; i < 96 * 64; i += 256) {
        int j = i / 64, kk = i % 64;
        sWd[j][kk] = W_d[j * UNITS + k0 + kk];
    }
    __syncthreads();
    const int kk = tid & 63;
    const int cc0 = (tid >> 6) * 16;
    for (int cc = cc0; cc < cc0 + 16; ++cc) {
        float acc = 0.f;
#pragma unroll 12
        for (int j = 0; j < 96; ++j) acc += sWih[cc][j] * sWd[j][kk];
        int c = c0 + cc;
        int u = ((c >> 6) << 4) + (c & 15);
        int g = (c >> 4) & 3;
        int r = g * UNITS + u;
        BeffT[(size_t)c * UNITS + k0 + kk] = (bf16_t)(W_hh[(size_t)r * UNITS + k0 + kk] + acc);
    }
}

// rows 3072..3199 of BeffT: W_d rows then zero pad
__global__ void prep_wdt(const float* __restrict__ W_d, bf16_t* __restrict__ BeffT) {
    int idx = blockIdx.x * 256 + threadIdx.x; // 128*768
    int c = idx / UNITS, k = idx % UNITS;
    float v = (c < NPRED) ? W_d[c * UNITS + k] : 0.f;
    BeffT[(size_t)(NCOLS + c) * UNITS + k] = (bf16_t)v;
}

// swizzle linear [c][K] (c pre-reordered) -> B-fragment order:
// elem((((nw*Knk + kf)*4 + f)*64 + l)*8 + j) = src[c][k],
//   c = (nw>>1)*128 + (nw&1)*64 + f*16 + (l&15),  k = kf*32 + (l>>4)*8 + j
__global__ void prep_swz(const bf16_t* __restrict__ src, bf16_t* __restrict__ dst,
                         int Knk, int K, int total) {
    int idx = blockIdx.x * 256 + threadIdx.x;
    if (idx >= total) return;
    int j = idx & 7;
    int l = (idx >> 3) & 63;
    int fg = idx >> 9;
    int f = fg & 3;
    int rest = fg >> 2;
    int kf = rest % Knk;
    int nw = rest / Knk;
    int c = (nw >> 1) * 128 + (nw & 1) * 64 + f * 16 + (l & 15);
    int k = kf * 32 + (l >> 4) * 8 + j;
    dst[idx] = src[(size_t)c * K + k];
}

__global__ void zero_ctr(int* __restrict__ c) {
    c[threadIdx.x] = 0;   // 256 ints = 4 groups x 64 steps
}

// ---------------- persistent kernel: all 64 steps in one launch ---------------
// Exploits batch independence: 4 groups (512-row m-stripes) of 50 blocks each
// synchronize only among themselves via device-scope atomic barriers.
// Block = 512 rows x 64 cols, 8 waves of 64x64, 512 threads.
// B-stripe (64 cols x K=768, frag order) resident in LDS for all steps (96 KB).
// c-state lives in registers across all 64 steps (no memory traffic).
// Mapping: xcd = bid&7 -> group mt = xcd>>1, so each group's h traffic stays
// within one XCD pair (perf heuristic only; correctness is placement-independent
// because all inter-block sync uses device-scope atomics + fences).
__global__ __launch_bounds__(512, 2)
void lstm_persist(const bf16_t* __restrict__ x0s,
                  const bf16_t* __restrict__ B0s,
                  const bf16_t* __restrict__ Bs,
                  const float* __restrict__ b0r,
                  const float* __restrict__ beffr,
                  const float* __restrict__ b_d,
                  bf16_t* __restrict__ h0,
                  bf16_t* __restrict__ h1,
                  float* __restrict__ out,
                  int* __restrict__ ctr)
{
    __shared__ __align__(16) bf16_t smem[24 * 4 * 512];   // 49152 elems = 96 KB

    const int tid = threadIdx.x;
    const int wr   = tid >> 6;          // 0..7 : 64-row slice within 512-row stripe
    const int lane = tid & 63;
    const int l15 = lane & 15, l4 = lane >> 4;

    const int bid  = blockIdx.x;        // 200 blocks
    const int xcd  = bid & 7;
    const int ii   = bid >> 3;          // 0..24
    const int mt   = xcd >> 1;          // group 0..3 (512-row stripe)
    const int nt64 = (xcd & 1) * 25 + ii;  // 0..49 : 64-col stripe
    const bool is_pred = (nt64 >= 48);
    const int nt  = nt64 >> 1;          // 128-col tile index (0..24)
    const int wcb = nt64 & 1;           // which 64-col half of the 128-col tile

    // ---- stage this block's B-stripe into LDS (no sync needed until s=1:
    //      barrier_step(0)'s __syncthreads covers it) ----
    {
        const f32x4* src = (const f32x4*)(Bs + (size_t)nt64 * 49152);
        f32x4* dst = (f32x4*)smem;
        for (int i = tid; i < 6144; i += 512) dst[i] = src[i];
    }

    // ---- per-thread constants ----
    int aoffh[4], aoff0[4];
#pragma unroll
    for (int i = 0; i < 4; ++i) {
        int mf = mt * 32 + wr * 4 + i;
        aoffh[i] = (mf * 24) * 512 + lane * 8;
        aoff0[i] = (mf * 3) * 512 + lane * 8;
    }
    int boff0[4];
#pragma unroll
    for (int f = 0; f < 4; ++f)
        boff0[f] = ((nt64 * 12 + f) * 64 + lane) * 8;   // B0s global frag offsets (s=0)

    float bi0[4], biS[4];
    if (!is_pred) {
#pragma unroll
        for (int f = 0; f < 4; ++f) {
            int idx = nt * 128 + wcb * 64 + f * 16 + l15;
            bi0[f] = b0r[idx];
            biS[f] = beffr[idx];
        }
    } else {
#pragma unroll
        for (int f = 0; f < 4; ++f) {
            int j = wcb * 64 + f * 16 + l15;
            biS[f] = (j < NPRED) ? b_d[j] : 0.f;
            bi0[f] = 0.f;
        }
    }

    const int kq = wcb * 2 + (l15 >> 3);
    const int jj = l15 & 7;

    f32x4 creg[4];          // persistent cell state for this thread's tile
#pragma unroll
    for (int i = 0; i < 4; ++i) creg[i] = f32x4{0.f, 0.f, 0.f, 0.f};

    int* cbase = ctr + mt * 64;

    f32x4 acc[4][4];

#define ZACC() do {                                                                  \
        _Pragma("unroll") for (int _i = 0; _i < 4; ++_i)                             \
        _Pragma("unroll") for (int _j = 0; _j < 4; ++_j)                             \
            acc[_i][_j] = f32x4{0.f, 0.f, 0.f, 0.f};                                 \
    } while (0)

#define LOADK_H(BUF, KT) do {                                                        \
        _Pragma("unroll")                                                            \
        for (int _i = 0; _i < 4; ++_i)                                               \
            afr[BUF][_i] = *(const s16x8*)(hA + aoffh[_i] + (size_t)(KT) * 512);     \
        _Pragma("unroll")                                                            \
        for (int _f = 0; _f < 4; ++_f)                                               \
            bfr[BUF][_f] = *(const s16x8*)(smem + ((KT) * 4 + _f) * 512 + lane * 8); \
    } while (0)

#define LOADK_0(BUF, KT) do {                                                        \
        _Pragma("unroll")                                                            \
        for (int _i = 0; _i < 4; ++_i)                                               \
            afr[BUF][_i] = *(const s16x8*)(x0s + aoff0[_i] + (size_t)(KT) * 512);    \
        _Pragma("unroll")                                                            \
        for (int _f = 0; _f < 4; ++_f)                                               \
            bfr[BUF][_f] = *(const s16x8*)(B0s + boff0[_f] + (size_t)(KT) * 2048);   \
    } while (0)

#define MF(BUF) do {                                                                 \
        _Pragma("unroll")                                                            \
        for (int _i = 0; _i < 4; ++_i)                                               \
            _Pragma("unroll")                                                        \
            for (int _j = 0; _j < 4; ++_j)                                           \
                acc[_i][_j] = __builtin_amdgcn_mfma_f32_16x16x32_bf16(               \
                    afr[BUF][_i], bfr[BUF][_j], acc[_i][_j], 0, 0, 0);               \
    } while (0)

#define RUN3(NK, LOADK) do {                                                         \
        s16x8 afr[3][4], bfr[3][4];                                                  \
        LOADK(0, 0); LOADK(1, 1);                                                    \
        const int _nk3 = (NK) / 3;                                                   \
        for (int _b3 = 0; _b3 < _nk3; ++_b3) {                                       \
            const int _kt = _b3 * 3;                                                 \
            if (_kt + 2 < (NK)) LOADK(2, _kt + 2);                                   \
            MF(0);                                                                   \
            if (_kt + 3 < (NK)) LOADK(0, _kt + 3);                                   \
            MF(1);                                                                   \
            if (_kt + 4 < (NK)) LOADK(1, _kt + 4);                                   \
            MF(2);                                                                   \
        }                                                                            \
    } while (0)

#define GATE_EPI(HW, BI) do {                                                        \
        _Pragma("unroll")                                                            \
        for (int _i = 0; _i < 4; ++_i) {                                             \
            const int _mf = mt * 32 + wr * 4 + _i;                                   \
            bf16_t* _hb = (HW) + (size_t)(_mf * 24 + nt) * 512;                      \
            _Pragma("unroll")                                                        \
            for (int _r = 0; _r < 4; ++_r) {                                         \
                float _gi = acc[_i][0][_r] + (BI)[0];                                \
                float _gf = acc[_i][1][_r] + (BI)[1];                                \
                float _gg = acc[_i][2][_r] + (BI)[2];                                \
                float _go = acc[_i][3][_r] + (BI)[3];                                \
                float _si = sigf(_gi);                                               \
                float _sf = sigf(_gf);                                               \
                float _tg = tanh_fast(_gg);                                          \
                float _so = sigf(_go);                                               \
                float _cn = _sf * creg[_i][_r] + _si * _tg;                          \
                creg[_i][_r] = _cn;                                                  \
                int _lp = (l4 * 4 + _r) | (kq << 4);                                 \
                _hb[_lp * 8 + jj] = (bf16_t)(_so * tanh_fast(_cn));                  \
            }                                                                        \
        }                                                                            \
    } while (0)

#define PRED_EPI(TCOL) do {                                                          \
        _Pragma("unroll")                                                            \
        for (int _f = 0; _f < 4; ++_f) {                                             \
            int _j = wcb * 64 + _f * 16 + l15;                                       \
            if (_j < NPRED) {                                                        \
                _Pragma("unroll")                                                    \
                for (int _i = 0; _i < 4; ++_i)                                       \
                    _Pragma("unroll")                                                \
                    for (int _r = 0; _r < 4; ++_r) {                                 \
                        int _row = mt * 512 + wr * 64 + _i * 16 + l4 * 4 + _r;       \
                        out[((size_t)_row * 64 + (TCOL)) * NPRED + _j] =             \
                            acc[_i][_f][_r] + biS[_f];                               \
                    }                                                                \
            }                                                                        \
        }                                                                            \
    } while (0)

    auto barrier_step = [&](int s) {
        __syncthreads();                       // all waves' stores drained to L2
        if (tid == 0) {
            __threadfence();                   // release: write back L2 (device scope)
            __hip_atomic_fetch_add(cbase + s, 1, __ATOMIC_RELEASE,
                                   __HIP_MEMORY_SCOPE_AGENT);
            int it = 0;
            while (__hip_atomic_load(cbase + s, __ATOMIC_ACQUIRE,
                                     __HIP_MEMORY_SCOPE_AGENT) < 50) {
                __builtin_amdgcn_s_sleep(2);
                if (++it > (1 << 22)) break;   // failsafe: wrong answer > hang
            }
            __threadfence();                   // acquire: invalidate stale L1/L2
        }
        __syncthreads();
    };

    // ---- step 0: gates from x0 (Knk=3), c=h=0; preds idle ----
    if (!is_pred) {
        ZACC();
        RUN3(3, LOADK_0);
        GATE_EPI(h1, bi0);
    }
    barrier_step(0);

    // ---- steps 1..63 ----
    for (int s = 1; s < 64; ++s) {
        const bf16_t* hA = (s & 1) ? h1 : h0;
        ZACC();
        RUN3(24, LOADK_H);
        if (!is_pred) {
            bf16_t* hW = ((s + 1) & 1) ? h1 : h0;
            GATE_EPI(hW, biS);
        } else {
            PRED_EPI(s - 1);
        }
        barrier_step(s);
    }

    // ---- step 64: final prediction from h_64 (in h0) ----
    if (is_pred) {
        const bf16_t* hA = h0;
        ZACC();
        RUN3(24, LOADK_H);
        PRED_EPI(63);
    }

#undef ZACC
#undef LOADK_H
#undef LOADK_0
#undef MF
#undef RUN3
#undef GATE_EPI
#undef PRED_EPI
}

extern "C" void kernel_launch(void* const* d_in, const int* in_sizes, int n_in,
                              void* d_out, int out_size, void* d_ws, size_t ws_size,
                              hipStream_t stream)
{
    const float* inputs = (const float*)d_in[0];
    const float* W_ih   = (const float*)d_in[1];
    const float* W_hh   = (const float*)d_in[2];
    const float* b_ih   = (const float*)d_in[3];
    const float* b_hh   = (const float*)d_in[4];
    const float* W_d    = (const float*)d_in[5];
    const float* b_d    = (const float*)d_in[6];
    float* out = (float*)d_out;

    char* ws = (char*)d_ws;
    size_t off = 0;
    auto alloc = [&](size_t bytes) -> char* {
        char* p = ws + off;
        off = (off + bytes + 255) & ~(size_t)255;
        return p;
    };
    bf16_t* B0T   = (bf16_t*)alloc((size_t)NCOLS * 96 * 2);       // linear temp
    bf16_t* B0s   = (bf16_t*)alloc((size_t)NCOLS * 96 * 2);       // frag-swizzled
    bf16_t* BeffT = (bf16_t*)alloc((size_t)3200 * UNITS * 2);     // linear temp
    bf16_t* Bs    = (bf16_t*)alloc((size_t)3200 * UNITS * 2);     // frag-swizzled
    bf16_t* x0s   = (bf16_t*)alloc((size_t)MROWS * 96 * 2);       // frag layout
    bf16_t* h0    = (bf16_t*)alloc((size_t)MROWS * UNITS * 2);    // frag layout
    bf16_t* h1    = (bf16_t*)alloc((size_t)MROWS * UNITS * 2);
    float*  b0r   = (float*)alloc(NCOLS * 4);
    float*  beffr = (float*)alloc(NCOLS * 4);
    int*    ctr   = (int*)alloc(256 * 4);                         // 4 groups x 64 steps

    prep_b0   <<<(NCOLS * 96 + 255) / 256, 256, 0, stream>>>(W_ih, B0T);
    prep_swz  <<<(NCOLS * 96 + 255) / 256, 256, 0, stream>>>(B0T, B0s, 3, 96, NCOLS * 96);
    prep_x0   <<<(MROWS * 96) / 256, 256, 0, stream>>>(inputs, x0s);
    prep_bias <<<(NCOLS + 255) / 256, 256, 0, stream>>>(b_ih, b_hh, W_ih, b_d, b0r, beffr);
    prep_beff2<<<dim3(48, 12), 256, 0, stream>>>(W_hh, W_ih, W_d, BeffT);
    prep_wdt  <<<(128 * UNITS) / 256, 256, 0, stream>>>(W_d, BeffT);
    prep_swz  <<<(3200 * UNITS + 255) / 256, 256, 0, stream>>>(BeffT, Bs, 24, UNITS, 3200 * UNITS);
    zero_ctr  <<<1, 256, 0, stream>>>(ctr);

    // one persistent kernel runs all 64 steps; 200 blocks <= 256 CUs (1 block/CU,
    // LDS-limited), so all blocks are co-resident and the group barriers are safe.
    lstm_persist<<<200, 512, 0, stream>>>(x0s, B0s, Bs, b0r, beffr, b_d,
                                          h0, h1, out, ctr);

    (void)ws_size; (void)in_sizes; (void)n_in; (void)out_size;
}

// Round 2
// 1299.049 us; speedup vs baseline: 1.4808x; 1.4808x over previous
//
#include <hip/hip_runtime.h>
#include <hip/hip_bf16.h>
#include <stdint.h>

typedef __hip_bfloat16 bf16_t;
typedef __attribute__((ext_vector_type(4))) float f32x4;
typedef __attribute__((ext_vector_type(8))) short s16x8;

#define UNITS 768
#define NCOLS 3072        // 4*UNITS (gates, reordered)
#define NPRED 96
#define MROWS 2048

__device__ __forceinline__ float sigf(float x) {
    return __builtin_amdgcn_rcpf(1.f + __expf(-x));
}
__device__ __forceinline__ float tanh_fast(float x) {
    return 1.f - 2.f * __builtin_amdgcn_rcpf(1.f + __expf(2.f * x));
}

// ---------------- prep kernels (once per launch, off critical path) ---------------

// B0T[c][k] = W_ih[g*768+u][k], c-reordered (linear), K=96
__global__ void prep_b0(const float* __restrict__ W_ih, bf16_t* __restrict__ B0T) {
    int idx = blockIdx.x * 256 + threadIdx.x;
    if (idx >= NCOLS * 96) return;
    int c = idx / 96, k = idx % 96;
    int u = ((c >> 6) << 4) + (c & 15);
    int g = (c >> 4) & 3;
    B0T[idx] = (bf16_t)W_ih[(g * UNITS + u) * 96 + k];
}

// x0 in A-fragment layout: elem((mf*3+kf)*512 + l*8 + j) = x[mf*16+(l&15)][kf*32+(l>>4)*8+j]
__global__ void prep_x0(const float* __restrict__ inputs, bf16_t* __restrict__ x0) {
    int idx = blockIdx.x * 256 + threadIdx.x; // 2048*96 = 196608 exactly
    int j = idx & 7;
    int l = (idx >> 3) & 63;
    int fg = idx >> 9;          // mf*3 + kf
    int kf = fg % 3;
    int mf = fg / 3;
    int m = mf * 16 + (l & 15);
    int k = kf * 32 + (l >> 4) * 8 + j;
    x0[idx] = (bf16_t)inputs[(m * 24 + 23) * 96 + k];
}

__global__ void prep_bias(const float* __restrict__ b_ih, const float* __restrict__ b_hh,
                          const float* __restrict__ W_ih, const float* __restrict__ b_d,
                          float* __restrict__ b0_r, float* __restrict__ beff_r) {
    int c = blockIdx.x * 256 + threadIdx.x;
    if (c >= NCOLS) return;
    int u = ((c >> 6) << 4) + (c & 15);
    int g = (c >> 4) & 3;
    int r = g * UNITS + u;
    float v = b_ih[r] + b_hh[r];
    float acc = 0.f;
    for (int j = 0; j < 96; ++j) acc += W_ih[r * 96 + j] * b_d[j];
    b0_r[c] = v;
    beff_r[c] = v + acc;
}

// BeffT[c][k] = W_hh[r(c)][k] + sum_j W_ih[r(c)][j]*W_d[j][k]   (c<3072, LDS-tiled)
__global__ void prep_beff2(const float* __restrict__ W_hh, const float* __restrict__ W_ih,
                           const float* __restrict__ W_d, bf16_t* __restrict__ BeffT) {
    __shared__ float sWih[64][96];
    __shared__ float sWd[96][64];
    const int c0 = blockIdx.x * 64, k0 = blockIdx.y * 64;
    const int tid = threadIdx.x;
    for (int i = tid; i < 64 * 96; i += 256) {
        int cc = i / 96, j = i % 96;
        int c = c0 + cc;
        int u = ((c >> 6) << 4) + (c & 15);
        int g = (c >> 4) & 3;
        sWih[cc][j] = W_ih[(g * UNITS + u) * 96 + j];
    }
    for (int i = tid; i < 96 * 64; i += 256) {
        int j = i / 64, kk = i % 64;
        sWd[j][kk] = W_d[j * UNITS + k0 + kk];
    }
    __syncthreads();
    const int kk = tid & 63;
    const int cc0 = (tid >> 6) * 16;
    for (int cc = cc0; cc < cc0 + 16; ++cc) {
        float acc = 0.f;
#pragma unroll 12
        for (int j = 0; j < 96; ++j) acc += sWih[cc][j] * sWd[j][kk];
        int c = c0 + cc;
        int u = ((c >> 6) << 4) + (c & 15);
        int g = (c >> 4) & 3;
        int r = g * UNITS + u;
        BeffT[(size_t)c * UNITS + k0 + kk] = (bf16_t)(W_hh[(size_t)r * UNITS + k0 + kk] + acc);
    }
}

// rows 3072..3199 of BeffT: W_d rows then zero pad
__global__ void prep_wdt(const float* __restrict__ W_d, bf16_t* __restrict__ BeffT) {
    int idx = blockIdx.x * 256 + threadIdx.x; // 128*768
    int c = idx / UNITS, k = idx % UNITS;
    float v = (c < NPRED) ? W_d[c * UNITS + k] : 0.f;
    BeffT[(size_t)(NCOLS + c) * UNITS + k] = (bf16_t)v;
}

// swizzle linear [c][K] (c pre-reordered) -> B-fragment order:
// elem((((nw*Knk + kf)*4 + f)*64 + l)*8 + j) = src[c][k],
//   c = (nw>>1)*128 + (nw&1)*64 + f*16 + (l&15),  k = kf*32 + (l>>4)*8 + j
__global__ void prep_swz(const bf16_t* __restrict__ src, bf16_t* __restrict__ dst,
                         int Knk, int K, int total) {
    int idx = blockIdx.x * 256 + threadIdx.x;
    if (idx >= total) return;
    int j = idx & 7;
    int l = (idx >> 3) & 63;
    int fg = idx >> 9;
    int f = fg & 3;
    int rest = fg >> 2;
    int kf = rest % Knk;
    int nw = rest / Knk;
    int c = (nw >> 1) * 128 + (nw & 1) * 64 + f * 16 + (l & 15);
    int k = kf * 32 + (l >> 4) * 8 + j;
    dst[idx] = src[(size_t)c * K + k];
}

__global__ void zero_ctr(int* __restrict__ c) {
    c[threadIdx.x] = 0;   // 256 ints = 4 groups x 64 steps
}

// ---------------- persistent kernel: all 64 steps in one launch ---------------
// 4 groups (512-row m-stripes) of 50 blocks synchronize via per-group counters.
// Block = 512 rows x 64 cols, 8 waves of 64x64, 512 threads.
// B-stripe (64 cols x K=768, frag order) resident in LDS for all steps (96 KB).
// c-state lives in registers across all 64 steps.
//
// Barrier protocol (the round-1 fix): exactly ONE buffer_wbl2 (via the RELEASE
// fetch_add) and ONE buffer_inv (via the final ACQUIRE load) per block per step.
// Polling uses RELAXED agent loads (global_load sc1 — reads the coherent point,
// NO cache invalidation). Round 1's ACQUIRE-per-poll invalidated the XCD L2
// continuously, forcing all h reads to L3 every step (29 us/step).
__global__ __launch_bounds__(512, 2)
void lstm_persist(const bf16_t* __restrict__ x0s,
                  const bf16_t* __restrict__ B0s,
                  const bf16_t* __restrict__ Bs,
                  const float* __restrict__ b0r,
                  const float* __restrict__ beffr,
                  const float* __restrict__ b_d,
                  bf16_t* __restrict__ h0,
                  bf16_t* __restrict__ h1,
                  float* __restrict__ out,
                  int* __restrict__ ctr)
{
    __shared__ __align__(16) bf16_t smem[24 * 4 * 512];   // 49152 elems = 96 KB

    const int tid = threadIdx.x;
    const int wr   = tid >> 6;          // 0..7 : 64-row slice within 512-row stripe
    const int lane = tid & 63;
    const int l15 = lane & 15, l4 = lane >> 4;

    const int bid  = blockIdx.x;        // 200 blocks
    const int xcd  = bid & 7;
    const int ii   = bid >> 3;          // 0..24
    const int mt   = xcd >> 1;          // group 0..3 (512-row stripe)
    const int nt64 = (xcd & 1) * 25 + ii;  // 0..49 : 64-col stripe
    const bool is_pred = (nt64 >= 48);
    const int nt  = nt64 >> 1;          // 128-col tile index (0..24)
    const int wcb = nt64 & 1;           // which 64-col half of the 128-col tile

    // ---- stage this block's B-stripe into LDS (no sync needed until s=1:
    //      barrier_step(0)'s __syncthreads covers it) ----
    {
        const f32x4* src = (const f32x4*)(Bs + (size_t)nt64 * 49152);
        f32x4* dst = (f32x4*)smem;
        for (int i = tid; i < 6144; i += 512) dst[i] = src[i];
    }

    // ---- per-thread constants ----
    int aoffh[4], aoff0[4];
#pragma unroll
    for (int i = 0; i < 4; ++i) {
        int mf = mt * 32 + wr * 4 + i;
        aoffh[i] = (mf * 24) * 512 + lane * 8;
        aoff0[i] = (mf * 3) * 512 + lane * 8;
    }
    int boff0[4];
#pragma unroll
    for (int f = 0; f < 4; ++f)
        boff0[f] = ((nt64 * 12 + f) * 64 + lane) * 8;   // B0s global frag offsets (s=0)

    float bi0[4], biS[4];
    if (!is_pred) {
#pragma unroll
        for (int f = 0; f < 4; ++f) {
            int idx = nt * 128 + wcb * 64 + f * 16 + l15;
            bi0[f] = b0r[idx];
            biS[f] = beffr[idx];
        }
    } else {
#pragma unroll
        for (int f = 0; f < 4; ++f) {
            int j = wcb * 64 + f * 16 + l15;
            biS[f] = (j < NPRED) ? b_d[j] : 0.f;
            bi0[f] = 0.f;
        }
    }

    const int kq = wcb * 2 + (l15 >> 3);
    const int jj = l15 & 7;

    f32x4 creg[4];          // persistent cell state for this thread's tile
#pragma unroll
    for (int i = 0; i < 4; ++i) creg[i] = f32x4{0.f, 0.f, 0.f, 0.f};

    int* cbase = ctr + mt * 64;

    f32x4 acc[4][4];

#define ZACC() do {                                                                  \
        _Pragma("unroll") for (int _i = 0; _i < 4; ++_i)                             \
        _Pragma("unroll") for (int _j = 0; _j < 4; ++_j)                             \
            acc[_i][_j] = f32x4{0.f, 0.f, 0.f, 0.f};                                 \
    } while (0)

#define LOADK_H(BUF, KT) do {                                                        \
        _Pragma("unroll")                                                            \
        for (int _i = 0; _i < 4; ++_i)                                               \
            afr[BUF][_i] = *(const s16x8*)(hA + aoffh[_i] + (size_t)(KT) * 512);     \
        _Pragma("unroll")                                                            \
        for (int _f = 0; _f < 4; ++_f)                                               \
            bfr[BUF][_f] = *(const s16x8*)(smem + ((KT) * 4 + _f) * 512 + lane * 8); \
    } while (0)

#define LOADK_0(BUF, KT) do {                                                        \
        _Pragma("unroll")                                                            \
        for (int _i = 0; _i < 4; ++_i)                                               \
            afr[BUF][_i] = *(const s16x8*)(x0s + aoff0[_i] + (size_t)(KT) * 512);    \
        _Pragma("unroll")                                                            \
        for (int _f = 0; _f < 4; ++_f)                                               \
            bfr[BUF][_f] = *(const s16x8*)(B0s + boff0[_f] + (size_t)(KT) * 2048);   \
    } while (0)

#define MF(BUF) do {                                                                 \
        _Pragma("unroll")                                                            \
        for (int _i = 0; _i < 4; ++_i)                                               \
            _Pragma("unroll")                                                        \
            for (int _j = 0; _j < 4; ++_j)                                           \
                acc[_i][_j] = __builtin_amdgcn_mfma_f32_16x16x32_bf16(               \
                    afr[BUF][_i], bfr[BUF][_j], acc[_i][_j], 0, 0, 0);               \
    } while (0)

#define RUN3(NK, LOADK) do {                                                         \
        s16x8 afr[3][4], bfr[3][4];                                                  \
        LOADK(0, 0); LOADK(1, 1);                                                    \
        const int _nk3 = (NK) / 3;                                                   \
        for (int _b3 = 0; _b3 < _nk3; ++_b3) {                                       \
            const int _kt = _b3 * 3;                                                 \
            if (_kt + 2 < (NK)) LOADK(2, _kt + 2);                                   \
            MF(0);                                                                   \
            if (_kt + 3 < (NK)) LOADK(0, _kt + 3);                                   \
            MF(1);                                                                   \
            if (_kt + 4 < (NK)) LOADK(1, _kt + 4);                                   \
            MF(2);                                                                   \
        }                                                                            \
    } while (0)

#define GATE_EPI(HW, BI) do {                                                        \
        _Pragma("unroll")                                                            \
        for (int _i = 0; _i < 4; ++_i) {                                             \
            const int _mf = mt * 32 + wr * 4 + _i;                                   \
            bf16_t* _hb = (HW) + (size_t)(_mf * 24 + nt) * 512;                      \
            _Pragma("unroll")                                                        \
            for (int _r = 0; _r < 4; ++_r) {                                         \
                float _gi = acc[_i][0][_r] + (BI)[0];                                \
                float _gf = acc[_i][1][_r] + (BI)[1];                                \
                float _gg = acc[_i][2][_r] + (BI)[2];                                \
                float _go = acc[_i][3][_r] + (BI)[3];                                \
                float _si = sigf(_gi);                                               \
                float _sf = sigf(_gf);                                               \
                float _tg = tanh_fast(_gg);                                          \
                float _so = sigf(_go);                                               \
                float _cn = _sf * creg[_i][_r] + _si * _tg;                          \
                creg[_i][_r] = _cn;                                                  \
                int _lp = (l4 * 4 + _r) | (kq << 4);                                 \
                _hb[_lp * 8 + jj] = (bf16_t)(_so * tanh_fast(_cn));                  \
            }                                                                        \
        }                                                                            \
    } while (0)

#define PRED_EPI(TCOL) do {                                                          \
        _Pragma("unroll")                                                            \
        for (int _f = 0; _f < 4; ++_f) {                                             \
            int _j = wcb * 64 + _f * 16 + l15;                                       \
            if (_j < NPRED) {                                                        \
                _Pragma("unroll")                                                    \
                for (int _i = 0; _i < 4; ++_i)                                       \
                    _Pragma("unroll")                                                \
                    for (int _r = 0; _r < 4; ++_r) {                                 \
                        int _row = mt * 512 + wr * 64 + _i * 16 + l4 * 4 + _r;       \
                        out[((size_t)_row * 64 + (TCOL)) * NPRED + _j] =             \
                            acc[_i][_f][_r] + biS[_f];                               \
                    }                                                                \
            }                                                                        \
        }                                                                            \
    } while (0)

    // One wbl2 (release add, producers only) + one inv (final acquire load) per
    // block per step. Poll is RELAXED: global_load sc1 reads the coherent point
    // without invalidating anything.
    auto barrier_step = [&](int s) {
        __syncthreads();                       // all waves' h stores vmcnt-retired
        if (tid == 0) {
            if (is_pred) {
                // produces nothing consumed in-kernel: no flush needed
                __hip_atomic_fetch_add(cbase + s, 1, __ATOMIC_RELAXED,
                                       __HIP_MEMORY_SCOPE_AGENT);
            } else {
                // release: buffer_wbl2 sc1 flushes this XCD's dirty h lines to L3
                __hip_atomic_fetch_add(cbase + s, 1, __ATOMIC_RELEASE,
                                       __HIP_MEMORY_SCOPE_AGENT);
            }
            int it = 0;
            while (__hip_atomic_load(cbase + s, __ATOMIC_RELAXED,
                                     __HIP_MEMORY_SCOPE_AGENT) < 50) {
                __builtin_amdgcn_s_sleep(8);
                if (++it > (1 << 24)) break;   // failsafe: wrong answer > hang
            }
            // acquire: single buffer_inv sc1 -> stale clean h lines dropped;
            // subsequent cached loads refetch once from L3, then L2-resident.
            (void)__hip_atomic_load(cbase + s, __ATOMIC_ACQUIRE,
                                    __HIP_MEMORY_SCOPE_AGENT);
        }
        __syncthreads();
    };

    // ---- step 0: gates from x0 (Knk=3), c=h=0; preds idle ----
    if (!is_pred) {
        ZACC();
        RUN3(3, LOADK_0);
        GATE_EPI(h1, bi0);
    }
    barrier_step(0);

    // ---- steps 1..63 ----
    for (int s = 1; s < 64; ++s) {
        const bf16_t* hA = (s & 1) ? h1 : h0;
        ZACC();
        RUN3(24, LOADK_H);
        if (!is_pred) {
            bf16_t* hW = ((s + 1) & 1) ? h1 : h0;
            GATE_EPI(hW, biS);
        } else {
            PRED_EPI(s - 1);
        }
        barrier_step(s);
    }

    // ---- step 64: final prediction from h_64 (in h0) ----
    if (is_pred) {
        const bf16_t* hA = h0;
        ZACC();
        RUN3(24, LOADK_H);
        PRED_EPI(63);
    }

#undef ZACC
#undef LOADK_H
#undef LOADK_0
#undef MF
#undef RUN3
#undef GATE_EPI
#undef PRED_EPI
}

extern "C" void kernel_launch(void* const* d_in, const int* in_sizes, int n_in,
                              void* d_out, int out_size, void* d_ws, size_t ws_size,
                              hipStream_t stream)
{
    const float* inputs = (const float*)d_in[0];
    const float* W_ih   = (const float*)d_in[1];
    const float* W_hh   = (const float*)d_in[2];
    const float* b_ih   = (const float*)d_in[3];
    const float* b_hh   = (const float*)d_in[4];
    const float* W_d    = (const float*)d_in[5];
    const float* b_d    = (const float*)d_in[6];
    float* out = (float*)d_out;

    char* ws = (char*)d_ws;
    size_t off = 0;
    auto alloc = [&](size_t bytes) -> char* {
        char* p = ws + off;
        off = (off + bytes + 255) & ~(size_t)255;
        return p;
    };
    bf16_t* B0T   = (bf16_t*)alloc((size_t)NCOLS * 96 * 2);       // linear temp
    bf16_t* B0s   = (bf16_t*)alloc((size_t)NCOLS * 96 * 2);       // frag-swizzled
    bf16_t* BeffT = (bf16_t*)alloc((size_t)3200 * UNITS * 2);     // linear temp
    bf16_t* Bs    = (bf16_t*)alloc((size_t)3200 * UNITS * 2);     // frag-swizzled
    bf16_t* x0s   = (bf16_t*)alloc((size_t)MROWS * 96 * 2);       // frag layout
    bf16_t* h0    = (bf16_t*)alloc((size_t)MROWS * UNITS * 2);    // frag layout
    bf16_t* h1    = (bf16_t*)alloc((size_t)MROWS * UNITS * 2);
    float*  b0r   = (float*)alloc(NCOLS * 4);
    float*  beffr = (float*)alloc(NCOLS * 4);
    int*    ctr   = (int*)alloc(256 * 4);                         // 4 groups x 64 steps

    prep_b0   <<<(NCOLS * 96 + 255) / 256, 256, 0, stream>>>(W_ih, B0T);
    prep_swz  <<<(NCOLS * 96 + 255) / 256, 256, 0, stream>>>(B0T, B0s, 3, 96, NCOLS * 96);
    prep_x0   <<<(MROWS * 96) / 256, 256, 0, stream>>>(inputs, x0s);
    prep_bias <<<(NCOLS + 255) / 256, 256, 0, stream>>>(b_ih, b_hh, W_ih, b_d, b0r, beffr);
    prep_beff2<<<dim3(48, 12), 256, 0, stream>>>(W_hh, W_ih, W_d, BeffT);
    prep_wdt  <<<(128 * UNITS) / 256, 256, 0, stream>>>(W_d, BeffT);
    prep_swz  <<<(3200 * UNITS + 255) / 256, 256, 0, stream>>>(BeffT, Bs, 24, UNITS, 3200 * UNITS);
    zero_ctr  <<<1, 256, 0, stream>>>(ctr);

    // one persistent kernel runs all 64 steps; 200 blocks <= 256 CUs (1 block/CU,
    // LDS-limited), so all blocks are co-resident and the group barriers are safe.
    lstm_persist<<<200, 512, 0, stream>>>(x0s, B0s, Bs, b0r, beffr, b_d,
                                          h0, h1, out, ctr);

    (void)ws_size; (void)in_sizes; (void)n_in; (void)out_size;
}